// Round 6
// baseline (1113.825 us; speedup 1.0000x reference)
//
#include <hip/hip_runtime.h>
#include <math.h>

// Problem constants
#define LAYERS 6
#define DMODEL 512
#define NHEAD 8
#define DHEAD 64
#define FFDIM 2048
#define BATCH 8
#define SEQ 1024
#define ROWS (BATCH * SEQ)   // 8192
#define EPS 1e-5f

typedef __attribute__((ext_vector_type(8))) short bf16x8;
typedef __attribute__((ext_vector_type(4))) float f32x4;

__device__ inline short f2bf(float f) {
    union { float f; unsigned u; } v; v.f = f;
    unsigned r = (v.u + 0x7FFFu + ((v.u >> 16) & 1u)) >> 16;
    return (short)r;
}

// async global(bf16,16B) -> LDS staging; data lands at wave-uniform base + lane*16
#define GLOAD_LDS16(g, l)                                                      \
    __builtin_amdgcn_global_load_lds(                                          \
        (__attribute__((address_space(1))) void*)(g),                          \
        (__attribute__((address_space(3))) void*)(l), 16, 0, 0)

// ---------------------------------------------------------------------------
// Weight transpose + fp32->bf16: src [L][K][N] f32 -> dst [L][N][K] bf16
// ---------------------------------------------------------------------------
__global__ void wtrans_kernel(const float* __restrict__ src, short* __restrict__ dst,
                              int K, int N) {
    __shared__ float t[32][33];
    const size_t mofs = (size_t)blockIdx.z * K * N;
    src += mofs; dst += mofs;
    int n0 = blockIdx.x * 32, k0 = blockIdx.y * 32;
    int tx = threadIdx.x, ty = threadIdx.y;
#pragma unroll
    for (int i = 0; i < 4; ++i)
        t[ty + 8 * i][tx] = src[(size_t)(k0 + ty + 8 * i) * N + n0 + tx];
    __syncthreads();
#pragma unroll
    for (int i = 0; i < 4; ++i)
        dst[(size_t)(n0 + ty + 8 * i) * K + k0 + tx] = f2bf(t[tx][ty + 8 * i]);
}

// ---------------------------------------------------------------------------
// Positional scan
// ---------------------------------------------------------------------------
__global__ void pos_scan_kernel(const int* __restrict__ mask, int* __restrict__ pos) {
    __shared__ int sm[SEQ];
    int b = blockIdx.x;
    int t = threadIdx.x;
    int v = (mask[b * SEQ + t] != 0) ? 1 : 0;
    sm[t] = v;
    __syncthreads();
    for (int off = 1; off < SEQ; off <<= 1) {
        int add = (t >= off) ? sm[t - off] : 0;
        __syncthreads();
        sm[t] += add;
        __syncthreads();
    }
    pos[b * SEQ + t] = sm[t] * v;
}

// ---------------------------------------------------------------------------
// x = x_in + sin_pos_table[pos]; writes fp32 master + bf16 copy
// ---------------------------------------------------------------------------
__global__ void add_pos_kernel(const float* __restrict__ xin, const int* __restrict__ pos,
                               float* __restrict__ xout, short* __restrict__ xb) {
    int bs = blockIdx.x;
    int t = threadIdx.x;
    int p = pos[bs];
    int d0 = t * 4;
    const float C = -logf(10000.0f) * (1.0f / 255.0f);  // half-1 = 255
    float4 xv = *(const float4*)(xin + (size_t)bs * DMODEL + d0);
    float e[4];
#pragma unroll
    for (int j = 0; j < 4; ++j) {
        int d = d0 + j;
        if (p == 0) {
            e[j] = 0.0f;
        } else {
            int dd = (d < 256) ? d : d - 256;
            float freq = expf((float)dd * C);
            float ang = (float)p * freq;
            e[j] = (d < 256) ? sinf(ang) : cosf(ang);
        }
    }
    float4 ov;
    ov.x = xv.x + e[0]; ov.y = xv.y + e[1]; ov.z = xv.z + e[2]; ov.w = xv.w + e[3];
    *(float4*)(xout + (size_t)bs * DMODEL + d0) = ov;
    short4 sb;
    sb.x = f2bf(ov.x); sb.y = f2bf(ov.y); sb.z = f2bf(ov.z); sb.w = f2bf(ov.w);
    *(short4*)(xb + (size_t)bs * DMODEL + d0) = sb;
}

// ===========================================================================
// LDS k-granule swizzle (GEMM kernels): granule q of row m lands at LDS
// position (q + ((m&15)>>1)) & 3; read at (quad + (lr>>1)) & 3. Read
// bank-groups balanced 8 accesses/bank -> conflict-free.
// ===========================================================================

// ---------------------------------------------------------------------------
// bf16 MFMA GEMM, 128x128 tile, BK=32, 256 thr, single-barrier double-buffer.
// ---------------------------------------------------------------------------
template <bool OUTBF16, bool BIAS, bool RELU>
__global__ __launch_bounds__(256) void gemm_bf16_kernel(const short* __restrict__ A,
                                                        const short* __restrict__ BT,
                                                        const float* __restrict__ bias,
                                                        void* __restrict__ Cv,
                                                        int M, int N, int K) {
    __shared__ __attribute__((aligned(16))) short Asm[2][128 * 32];
    __shared__ __attribute__((aligned(16))) short Bsm[2][128 * 32];
    const int tid = threadIdx.x;
    const int w = tid >> 6;
    const int lane = tid & 63;
    const int quad = lane >> 4;
    const int lr = lane & 15;
    const int m0 = blockIdx.y * 128;
    const int n0 = blockIdx.x * 128;
    const int wm = (w >> 1) * 64;
    const int wn = (w & 1) * 64;

    const int segr = lane >> 2;
    const int segk = (((lane & 3) - (lane >> 3)) & 3) * 8;
    const int sA0 = w * 2, sA1 = w * 2 + 1;
    const short* gA0 = A + (size_t)(m0 + sA0 * 16 + segr) * K + segk;
    const short* gA1 = A + (size_t)(m0 + sA1 * 16 + segr) * K + segk;
    const short* gB0 = BT + (size_t)(n0 + sA0 * 16 + segr) * K + segk;
    const short* gB1 = BT + (size_t)(n0 + sA1 * 16 + segr) * K + segk;
    const int lofs0 = sA0 * 512 + lane * 8;
    const int lofs1 = sA1 * 512 + lane * 8;
    const int gp = ((quad + (lr >> 1)) & 3) * 8;

    f32x4 acc[4][4];
#pragma unroll
    for (int i = 0; i < 4; ++i)
#pragma unroll
        for (int j = 0; j < 4; ++j) { acc[i][j][0] = 0.f; acc[i][j][1] = 0.f; acc[i][j][2] = 0.f; acc[i][j][3] = 0.f; }

    GLOAD_LDS16(gA0, &Asm[0][lofs0]);
    GLOAD_LDS16(gA1, &Asm[0][lofs1]);
    GLOAD_LDS16(gB0, &Bsm[0][lofs0]);
    GLOAD_LDS16(gB1, &Bsm[0][lofs1]);

    const int nk = K >> 5;
    for (int i = 0; i < nk; ++i) {
        __syncthreads();
        if (i + 1 < nk) {
            const int k1 = (i + 1) * 32;
            const int nb = (i + 1) & 1;
            GLOAD_LDS16(gA0 + k1, &Asm[nb][lofs0]);
            GLOAD_LDS16(gA1 + k1, &Asm[nb][lofs1]);
            GLOAD_LDS16(gB0 + k1, &Bsm[nb][lofs0]);
            GLOAD_LDS16(gB1 + k1, &Bsm[nb][lofs1]);
        }
        const int cur = i & 1;
        bf16x8 af[4], bfr[4];
#pragma unroll
        for (int mt = 0; mt < 4; ++mt)
            af[mt] = *(const bf16x8*)&Asm[cur][(wm + mt * 16 + lr) * 32 + gp];
#pragma unroll
        for (int nt = 0; nt < 4; ++nt)
            bfr[nt] = *(const bf16x8*)&Bsm[cur][(wn + nt * 16 + lr) * 32 + gp];
#pragma unroll
        for (int mt = 0; mt < 4; ++mt)
#pragma unroll
            for (int nt = 0; nt < 4; ++nt)
                acc[mt][nt] = __builtin_amdgcn_mfma_f32_16x16x32_bf16(af[mt], bfr[nt], acc[mt][nt], 0, 0, 0);
    }

    float bv[4];
    if (BIAS) {
#pragma unroll
        for (int nt = 0; nt < 4; ++nt) bv[nt] = bias[n0 + wn + nt * 16 + lr];
    }
#pragma unroll
    for (int mt = 0; mt < 4; ++mt)
#pragma unroll
        for (int nt = 0; nt < 4; ++nt)
#pragma unroll
            for (int r = 0; r < 4; ++r) {
                float v = acc[mt][nt][r];
                if (BIAS) v += bv[nt];
                if (RELU) v = fmaxf(v, 0.f);
                int row = m0 + wm + mt * 16 + quad * 4 + r;
                int col = n0 + wn + nt * 16 + lr;
                if (OUTBF16)
                    ((short*)Cv)[(size_t)row * N + col] = f2bf(v);
                else
                    ((float*)Cv)[(size_t)row * N + col] = v;
            }
}

// ---------------------------------------------------------------------------
// QKV GEMM: same 128x128 body, epilogue writes bf16 to head-major buffers
// qkv3[which][bh][s][dh]  (which: 0=q,1=k,2=v; bh = b*8+h).
// ---------------------------------------------------------------------------
__global__ __launch_bounds__(256) void gemm_qkv_kernel(const short* __restrict__ A,
                                                       const short* __restrict__ BT,
                                                       short* __restrict__ qkv3,
                                                       int M, int N, int K) {
    __shared__ __attribute__((aligned(16))) short Asm[2][128 * 32];
    __shared__ __attribute__((aligned(16))) short Bsm[2][128 * 32];
    const int tid = threadIdx.x;
    const int w = tid >> 6;
    const int lane = tid & 63;
    const int quad = lane >> 4;
    const int lr = lane & 15;
    const int m0 = blockIdx.y * 128;
    const int n0 = blockIdx.x * 128;
    const int wm = (w >> 1) * 64;
    const int wn = (w & 1) * 64;

    const int segr = lane >> 2;
    const int segk = (((lane & 3) - (lane >> 3)) & 3) * 8;
    const int sA0 = w * 2, sA1 = w * 2 + 1;
    const short* gA0 = A + (size_t)(m0 + sA0 * 16 + segr) * K + segk;
    const short* gA1 = A + (size_t)(m0 + sA1 * 16 + segr) * K + segk;
    const short* gB0 = BT + (size_t)(n0 + sA0 * 16 + segr) * K + segk;
    const short* gB1 = BT + (size_t)(n0 + sA1 * 16 + segr) * K + segk;
    const int lofs0 = sA0 * 512 + lane * 8;
    const int lofs1 = sA1 * 512 + lane * 8;
    const int gp = ((quad + (lr >> 1)) & 3) * 8;

    f32x4 acc[4][4];
#pragma unroll
    for (int i = 0; i < 4; ++i)
#pragma unroll
        for (int j = 0; j < 4; ++j) { acc[i][j][0] = 0.f; acc[i][j][1] = 0.f; acc[i][j][2] = 0.f; acc[i][j][3] = 0.f; }

    GLOAD_LDS16(gA0, &Asm[0][lofs0]);
    GLOAD_LDS16(gA1, &Asm[0][lofs1]);
    GLOAD_LDS16(gB0, &Bsm[0][lofs0]);
    GLOAD_LDS16(gB1, &Bsm[0][lofs1]);

    const int nk = K >> 5;
    for (int i = 0; i < nk; ++i) {
        __syncthreads();
        if (i + 1 < nk) {
            const int k1 = (i + 1) * 32;
            const int nb = (i + 1) & 1;
            GLOAD_LDS16(gA0 + k1, &Asm[nb][lofs0]);
            GLOAD_LDS16(gA1 + k1, &Asm[nb][lofs1]);
            GLOAD_LDS16(gB0 + k1, &Bsm[nb][lofs0]);
            GLOAD_LDS16(gB1 + k1, &Bsm[nb][lofs1]);
        }
        const int cur = i & 1;
        bf16x8 af[4], bfr[4];
#pragma unroll
        for (int mt = 0; mt < 4; ++mt)
            af[mt] = *(const bf16x8*)&Asm[cur][(wm + mt * 16 + lr) * 32 + gp];
#pragma unroll
        for (int nt = 0; nt < 4; ++nt)
            bfr[nt] = *(const bf16x8*)&Bsm[cur][(wn + nt * 16 + lr) * 32 + gp];
#pragma unroll
        for (int mt = 0; mt < 4; ++mt)
#pragma unroll
            for (int nt = 0; nt < 4; ++nt)
                acc[mt][nt] = __builtin_amdgcn_mfma_f32_16x16x32_bf16(af[mt], bfr[nt], acc[mt][nt], 0, 0, 0);
    }

#pragma unroll
    for (int nt = 0; nt < 4; ++nt) {
        const int col = n0 + wn + nt * 16 + lr;      // 0..1535
        const int which = col >> 9;
        const int h = (col >> 6) & 7;
        const int d = col & 63;
#pragma unroll
        for (int mt = 0; mt < 4; ++mt)
#pragma unroll
            for (int r = 0; r < 4; ++r) {
                int row = m0 + wm + mt * 16 + quad * 4 + r;
                int bb = row >> 10, s = row & 1023;
                qkv3[((size_t)(which * 64 + bb * 8 + h) * SEQ + s) * DHEAD + d] =
                    f2bf(acc[mt][nt][r]);
            }
    }
}

// ---------------------------------------------------------------------------
// bf16 MFMA GEMM, 64x128 tile (N=512 GEMMs). BK=32, 256 thr.
// ---------------------------------------------------------------------------
template <bool OUTBF16, bool BIAS, bool RELU>
__global__ __launch_bounds__(256) void gemm_bf16_m64_kernel(const short* __restrict__ A,
                                                            const short* __restrict__ BT,
                                                            const float* __restrict__ bias,
                                                            void* __restrict__ Cv,
                                                            int M, int N, int K) {
    __shared__ __attribute__((aligned(16))) short Asm[2][64 * 32];
    __shared__ __attribute__((aligned(16))) short Bsm[2][128 * 32];
    const int tid = threadIdx.x;
    const int w = tid >> 6;
    const int lane = tid & 63;
    const int quad = lane >> 4;
    const int lr = lane & 15;
    const int m0 = blockIdx.y * 64;
    const int n0 = blockIdx.x * 128;
    const int wm = (w >> 1) * 32;
    const int wn = (w & 1) * 64;

    const int segr = lane >> 2;
    const int segk = (((lane & 3) - (lane >> 3)) & 3) * 8;
    const short* gA  = A + (size_t)(m0 + w * 16 + segr) * K + segk;
    const short* gB0 = BT + (size_t)(n0 + (2 * w) * 16 + segr) * K + segk;
    const short* gB1 = BT + (size_t)(n0 + (2 * w + 1) * 16 + segr) * K + segk;
    const int lA  = w * 512 + lane * 8;
    const int lB0 = (2 * w) * 512 + lane * 8;
    const int lB1 = (2 * w + 1) * 512 + lane * 8;
    const int gp = ((quad + (lr >> 1)) & 3) * 8;

    f32x4 acc[2][4];
#pragma unroll
    for (int i = 0; i < 2; ++i)
#pragma unroll
        for (int j = 0; j < 4; ++j) { acc[i][j][0] = 0.f; acc[i][j][1] = 0.f; acc[i][j][2] = 0.f; acc[i][j][3] = 0.f; }

    GLOAD_LDS16(gA, &Asm[0][lA]);
    GLOAD_LDS16(gB0, &Bsm[0][lB0]);
    GLOAD_LDS16(gB1, &Bsm[0][lB1]);

    const int nk = K >> 5;
    for (int i = 0; i < nk; ++i) {
        __syncthreads();
        if (i + 1 < nk) {
            const int k1 = (i + 1) * 32;
            const int nb = (i + 1) & 1;
            GLOAD_LDS16(gA + k1, &Asm[nb][lA]);
            GLOAD_LDS16(gB0 + k1, &Bsm[nb][lB0]);
            GLOAD_LDS16(gB1 + k1, &Bsm[nb][lB1]);
        }
        const int cur = i & 1;
        bf16x8 af[2], bfr[4];
#pragma unroll
        for (int mt = 0; mt < 2; ++mt)
            af[mt] = *(const bf16x8*)&Asm[cur][(wm + mt * 16 + lr) * 32 + gp];
#pragma unroll
        for (int nt = 0; nt < 4; ++nt)
            bfr[nt] = *(const bf16x8*)&Bsm[cur][(wn + nt * 16 + lr) * 32 + gp];
#pragma unroll
        for (int mt = 0; mt < 2; ++mt)
#pragma unroll
            for (int nt = 0; nt < 4; ++nt)
                acc[mt][nt] = __builtin_amdgcn_mfma_f32_16x16x32_bf16(af[mt], bfr[nt], acc[mt][nt], 0, 0, 0);
    }

    float bv[4];
    if (BIAS) {
#pragma unroll
        for (int nt = 0; nt < 4; ++nt) bv[nt] = bias[n0 + wn + nt * 16 + lr];
    }
#pragma unroll
    for (int mt = 0; mt < 2; ++mt)
#pragma unroll
        for (int nt = 0; nt < 4; ++nt)
#pragma unroll
            for (int r = 0; r < 4; ++r) {
                float v = acc[mt][nt][r];
                if (BIAS) v += bv[nt];
                if (RELU) v = fmaxf(v, 0.f);
                int row = m0 + wm + mt * 16 + quad * 4 + r;
                int col = n0 + wn + nt * 16 + lr;
                if (OUTBF16)
                    ((short*)Cv)[(size_t)row * N + col] = f2bf(v);
                else
                    ((float*)Cv)[(size_t)row * N + col] = v;
            }
}

// ---------------------------------------------------------------------------
// bf16-MFMA flash attention v3: head-major dense q/k/v, QTILE=128, 256 thr
// (4 waves x 32 q-rows), 512 blocks = 2/CU. K staged via global_load_lds with
// 8-granule swizzle (stride 64, banks balanced); V register-transposed
// (conflict-free short2). Single barrier per tile, double-buffered.
// Grid 1D: bh = bx & 63 (XCD swizzle: 8 q-blocks of one bh share bx mod 8).
// ---------------------------------------------------------------------------
#define QTILE 128
__global__ __launch_bounds__(256) void attn_mfma_kernel(const short* __restrict__ qhm,
                                                        const short* __restrict__ khm,
                                                        const short* __restrict__ vhm,
                                                        const int* __restrict__ mask,
                                                        short* __restrict__ o) {
    __shared__ __attribute__((aligned(16))) short Ks[2][64 * 64];   // swizzled granules
    __shared__ __attribute__((aligned(16))) short Vt[2][64][72];    // [d][key]
    __shared__ __attribute__((aligned(16))) short Ps[4][16][72];    // per-wave P[m][key]
    __shared__ float Msf[2][64];

    const int bx = blockIdx.x;
    const int qt = bx >> 6;             // 0..7
    const int bh = bx & 63;
    const int b = bh >> 3, h = bh & 7;
    const int tid = threadIdx.x;
    const int w = tid >> 6;             // wave 0..3
    const int lane = tid & 63;
    const int quad = lane >> 4;
    const int lr = lane & 15;
    const size_t hbase = (size_t)bh * SEQ * DHEAD;
    const size_t seqrow = (size_t)b * SEQ;

    // ---- persistent Q fragments ----
    bf16x8 qf[2][2];
#pragma unroll
    for (int mt = 0; mt < 2; ++mt)
#pragma unroll
        for (int c = 0; c < 2; ++c)
            qf[mt][c] = *(const bf16x8*)(qhm + hbase +
                (size_t)(qt * QTILE + w * 32 + mt * 16 + lr) * DHEAD + c * 32 + quad * 8);

    // ---- K staging (global_load_lds): wave w, chunk j: row w*16+j*8+(lane>>3),
    //      LDS granule pos lane&7, source granule g' = ((lane&7)-j*4-(lane>>4))&7
    const int krow0 = w * 16 + (lane >> 3);
    const int kg0 = (((lane & 7) - (lane >> 4)) & 7) * 8;          // j=0
    const int kg1 = (((lane & 7) - 4 - (lane >> 4)) & 7) * 8;      // j=1
    const short* gK0 = khm + hbase + (size_t)krow0 * DHEAD + kg0;
    const short* gK1 = khm + hbase + (size_t)(krow0 + 8) * DHEAD + kg1;
    const int lK0 = w * 16 * 64 + lane * 8;
    const int lK1 = (w * 16 + 8) * 64 + lane * 8;
    // K fragment read position: granule (c*4+quad + (lr>>1)) & 7
    const int kp0 = ((quad + (lr >> 1)) & 7) * 8;          // c=0
    const int kp1 = ((4 + quad + (lr >> 1)) & 7) * 8;      // c=1

    // ---- V staging: thread -> key pair (tid&31), d-group (tid>>5) ----
    const int vkp = tid & 31;
    const int vdg = tid >> 5;
    const short* gV = vhm + hbase + (size_t)(2 * vkp) * DHEAD + vdg * 8;

    bf16x8 r0, r1;
    int mreg = 0;

    // prologue: stage tile 0 -> buffer 0
    GLOAD_LDS16(gK0, &Ks[0][lK0]);
    GLOAD_LDS16(gK1, &Ks[0][lK1]);
    {
        r0 = *(const bf16x8*)(gV);
        r1 = *(const bf16x8*)(gV + DHEAD);
#pragma unroll
        for (int i = 0; i < 8; ++i) {
            short2 p; p.x = r0[i]; p.y = r1[i];
            *(short2*)&Vt[0][vdg * 8 + i][vkp * 2] = p;
        }
        if (tid < 64) Msf[0][tid] = mask[seqrow + tid] ? 1.0f : 0.0f;
    }
    __syncthreads();

    f32x4 Oacc[2][4];
    float rs[2][4];
#pragma unroll
    for (int mt = 0; mt < 2; ++mt)
#pragma unroll
        for (int t2 = 0; t2 < 4; ++t2) { Oacc[mt][t2][0] = 0.f; Oacc[mt][t2][1] = 0.f; Oacc[mt][t2][2] = 0.f; Oacc[mt][t2][3] = 0.f; }
#pragma unroll
    for (int mt = 0; mt < 2; ++mt)
#pragma unroll
        for (int r = 0; r < 4; ++r) rs[mt][r] = 0.f;

    for (int kt = 0; kt < 16; ++kt) {
        const int cur = kt & 1;
        const int nb = cur ^ 1;
        const int ktn = (kt + 1) & 15;
        // ---- async K stage for next tile into other buffer ----
        GLOAD_LDS16(gK0 + (size_t)ktn * 64 * DHEAD, &Ks[nb][lK0]);
        GLOAD_LDS16(gK1 + (size_t)ktn * 64 * DHEAD, &Ks[nb][lK1]);
        // ---- V/mask register prefetch for next tile ----
        {
            const size_t ofs = (size_t)ktn * 64 * DHEAD;
            r0 = *(const bf16x8*)(gV + ofs);
            r1 = *(const bf16x8*)(gV + ofs + DHEAD);
            if (tid < 64) mreg = mask[seqrow + ktn * 64 + tid];
        }
        // ---- fragments from current buffer ----
        bf16x8 kf[2][4], vf[2][4];
#pragma unroll
        for (int t = 0; t < 4; ++t) {
            kf[0][t] = *(const bf16x8*)&Ks[cur][(lr + 16 * t) * 64 + kp0];
            kf[1][t] = *(const bf16x8*)&Ks[cur][(lr + 16 * t) * 64 + kp1];
            vf[0][t] = *(const bf16x8*)&Vt[cur][lr + 16 * t][quad * 8];
            vf[1][t] = *(const bf16x8*)&Vt[cur][lr + 16 * t][quad * 8 + 32];
        }
        float mv[4];
#pragma unroll
        for (int t = 0; t < 4; ++t) mv[t] = Msf[cur][lr + 16 * t];

#pragma unroll
        for (int mt = 0; mt < 2; ++mt) {
            f32x4 S[4];
#pragma unroll
            for (int t = 0; t < 4; ++t) { S[t][0] = 0.f; S[t][1] = 0.f; S[t][2] = 0.f; S[t][3] = 0.f; }
#pragma unroll
            for (int c = 0; c < 2; ++c)
#pragma unroll
                for (int t = 0; t < 4; ++t)
                    S[t] = __builtin_amdgcn_mfma_f32_16x16x32_bf16(qf[mt][c], kf[c][t], S[t], 0, 0, 0);
#pragma unroll
            for (int t = 0; t < 4; ++t)
#pragma unroll
                for (int r = 0; r < 4; ++r) {
                    float p = __expf(S[t][r] - 8.0f) * mv[t];
                    S[t][r] = p;
                    rs[mt][r] += p;
                }
#pragma unroll
            for (int t = 0; t < 4; ++t)
#pragma unroll
                for (int r = 0; r < 4; ++r)
                    Ps[w][quad * 4 + r][lr + 16 * t] = f2bf(S[t][r]);
            bf16x8 pa0 = *(const bf16x8*)&Ps[w][lr][quad * 8];
            bf16x8 pa1 = *(const bf16x8*)&Ps[w][lr][quad * 8 + 32];
#pragma unroll
            for (int t2 = 0; t2 < 4; ++t2) {
                Oacc[mt][t2] = __builtin_amdgcn_mfma_f32_16x16x32_bf16(pa0, vf[0][t2], Oacc[mt][t2], 0, 0, 0);
                Oacc[mt][t2] = __builtin_amdgcn_mfma_f32_16x16x32_bf16(pa1, vf[1][t2], Oacc[mt][t2], 0, 0, 0);
            }
        }
        // ---- write V/mask regs -> other buffer ----
        {
#pragma unroll
            for (int i = 0; i < 8; ++i) {
                short2 p; p.x = r0[i]; p.y = r1[i];
                *(short2*)&Vt[nb][vdg * 8 + i][vkp * 2] = p;
            }
            if (tid < 64) Msf[nb][tid] = mreg ? 1.0f : 0.0f;
        }
        __syncthreads();
    }

    // ---- epilogue ----
#pragma unroll
    for (int mt = 0; mt < 2; ++mt) {
        float inv[4];
#pragma unroll
        for (int r = 0; r < 4; ++r) {
            float v = rs[mt][r];
            v += __shfl_xor(v, 1);
            v += __shfl_xor(v, 2);
            v += __shfl_xor(v, 4);
            v += __shfl_xor(v, 8);
            inv[r] = 1.f / v;
        }
#pragma unroll
        for (int t2 = 0; t2 < 4; ++t2)
#pragma unroll
            for (int r = 0; r < 4; ++r) {
                int row = qt * QTILE + w * 32 + mt * 16 + quad * 4 + r;
                o[(seqrow + row) * DMODEL + h * DHEAD + 16 * t2 + lr] = f2bf(Oacc[mt][t2][r] * inv[r]);
            }
    }
}

// ---------------------------------------------------------------------------
// x = LayerNorm(tmp + x) * g + b; writes fp32 master (in-place) + bf16 copy
// ---------------------------------------------------------------------------
__global__ __launch_bounds__(64) void ln_kernel(const float* __restrict__ tmp,
                                                float* __restrict__ x,
                                                short* __restrict__ xb,
                                                const float* __restrict__ g,
                                                const float* __restrict__ bta) {
    const int row = blockIdx.x;
    const int t = threadIdx.x;
    const size_t base = (size_t)row * DMODEL + t * 8;
    float4 x0 = *(const float4*)(x + base);
    float4 x1 = *(const float4*)(x + base + 4);
    float4 t0 = *(const float4*)(tmp + base);
    float4 t1 = *(const float4*)(tmp + base + 4);
    float v[8];
    v[0] = x0.x + t0.x; v[1] = x0.y + t0.y; v[2] = x0.z + t0.z; v[3] = x0.w + t0.w;
    v[4] = x1.x + t1.x; v[5] = x1.y + t1.y; v[6] = x1.z + t1.z; v[7] = x1.w + t1.w;
    float s = 0.f, sq = 0.f;
#pragma unroll
    for (int i = 0; i < 8; ++i) { s += v[i]; sq += v[i] * v[i]; }
#pragma unroll
    for (int off = 1; off < 64; off <<= 1) {
        s += __shfl_xor(s, off);
        sq += __shfl_xor(sq, off);
    }
    float mu = s * (1.0f / DMODEL);
    float var = sq * (1.0f / DMODEL) - mu * mu;
    float r = rsqrtf(var + EPS);
    float4 g0 = *(const float4*)(g + t * 8);
    float4 g1 = *(const float4*)(g + t * 8 + 4);
    float4 b0 = *(const float4*)(bta + t * 8);
    float4 b1 = *(const float4*)(bta + t * 8 + 4);
    float ov[8];
    ov[0] = (v[0] - mu) * r * g0.x + b0.x;
    ov[1] = (v[1] - mu) * r * g0.y + b0.y;
    ov[2] = (v[2] - mu) * r * g0.z + b0.z;
    ov[3] = (v[3] - mu) * r * g0.w + b0.w;
    ov[4] = (v[4] - mu) * r * g1.x + b1.x;
    ov[5] = (v[5] - mu) * r * g1.y + b1.y;
    ov[6] = (v[6] - mu) * r * g1.z + b1.z;
    ov[7] = (v[7] - mu) * r * g1.w + b1.w;
    *(float4*)(x + base) = *(float4*)&ov[0];
    *(float4*)(x + base + 4) = *(float4*)&ov[4];
    bf16x8 ob;
#pragma unroll
    for (int i = 0; i < 8; ++i) ob[i] = f2bf(ov[i]);
    *(bf16x8*)(xb + base) = ob;
}

// ---------------------------------------------------------------------------
extern "C" void kernel_launch(void* const* d_in, const int* in_sizes, int n_in,
                              void* d_out, int out_size, void* d_ws, size_t ws_size,
                              hipStream_t stream) {
    const float* x_in  = (const float*)d_in[0];
    const int*   mask  = (const int*)d_in[3];
    const float* Wqkv  = (const float*)d_in[4];
    const float* Wfc   = (const float*)d_in[5];
    const float* bfc   = (const float*)d_in[6];
    const float* ln1_g = (const float*)d_in[7];
    const float* ln1_b = (const float*)d_in[8];
    const float* ln2_g = (const float*)d_in[9];
    const float* ln2_b = (const float*)d_in[10];
    const float* W1    = (const float*)d_in[11];
    const float* b1    = (const float*)d_in[12];
    const float* W2    = (const float*)d_in[13];
    const float* b2    = (const float*)d_in[14];

    float* x = (float*)d_out;  // fp32 activation master lives in d_out

    char* ws = (char*)d_ws;
    size_t ofs = 0;
    int*   pos   = (int*)ws;                 ofs += 65536;
    float* tmp   = (float*)(ws + ofs);       ofs += (size_t)ROWS * DMODEL * 4;
    short* xb    = (short*)(ws + ofs);       ofs += (size_t)ROWS * DMODEL * 2;
    short* qkv3  = (short*)(ws + ofs);       // [3][64][1024][64] bf16, 25.2 MB
    short* hb    = (short*)(ws + ofs);       // aliases qkv3..obuf (disjoint lifetime)
    ofs += (size_t)ROWS * 3 * DMODEL * 2;
    short* obuf  = (short*)(ws + ofs);       ofs += (size_t)ROWS * DMODEL * 2;
    short* WqkvT = (short*)(ws + ofs);       ofs += (size_t)LAYERS * DMODEL * 3 * DMODEL * 2;
    short* WfcT  = (short*)(ws + ofs);       ofs += (size_t)LAYERS * DMODEL * DMODEL * 2;
    short* W1T   = (short*)(ws + ofs);       ofs += (size_t)LAYERS * DMODEL * FFDIM * 2;
    short* W2T   = (short*)(ws + ofs);       ofs += (size_t)LAYERS * FFDIM * DMODEL * 2;

    wtrans_kernel<<<dim3(3 * DMODEL / 32, DMODEL / 32, LAYERS), dim3(32, 8), 0, stream>>>(
        Wqkv, WqkvT, DMODEL, 3 * DMODEL);
    wtrans_kernel<<<dim3(DMODEL / 32, DMODEL / 32, LAYERS), dim3(32, 8), 0, stream>>>(
        Wfc, WfcT, DMODEL, DMODEL);
    wtrans_kernel<<<dim3(FFDIM / 32, DMODEL / 32, LAYERS), dim3(32, 8), 0, stream>>>(
        W1, W1T, DMODEL, FFDIM);
    wtrans_kernel<<<dim3(DMODEL / 32, FFDIM / 32, LAYERS), dim3(32, 8), 0, stream>>>(
        W2, W2T, FFDIM, DMODEL);

    pos_scan_kernel<<<BATCH, SEQ, 0, stream>>>(mask, pos);
    add_pos_kernel<<<ROWS, 128, 0, stream>>>(x_in, pos, x, xb);

    short* qhm = qkv3;
    short* khm = qkv3 + (size_t)64 * SEQ * DHEAD;
    short* vhm = qkv3 + (size_t)128 * SEQ * DHEAD;

    for (int l = 0; l < LAYERS; ++l) {
        const short* wqkvT_l = WqkvT + (size_t)l * DMODEL * 3 * DMODEL;
        const short* wfcT_l  = WfcT + (size_t)l * DMODEL * DMODEL;
        const short* w1T_l   = W1T + (size_t)l * DMODEL * FFDIM;
        const short* w2T_l   = W2T + (size_t)l * FFDIM * DMODEL;
        const float* bfc_l   = bfc + (size_t)l * DMODEL;
        const float* b1_l    = b1 + (size_t)l * FFDIM;
        const float* b2_l    = b2 + (size_t)l * DMODEL;

        // qkv (head-major) = x @ Wqkv
        gemm_qkv_kernel<<<dim3(3 * DMODEL / 128, ROWS / 128), 256, 0, stream>>>(
            xb, wqkvT_l, qkv3, ROWS, 3 * DMODEL, DMODEL);
        // attention -> obuf ([B,S,H,dh] row-major)
        attn_mfma_kernel<<<512, 256, 0, stream>>>(qhm, khm, vhm, mask, obuf);
        // tmp = obuf @ Wfc + bfc
        gemm_bf16_m64_kernel<false, true, false><<<dim3(DMODEL / 128, ROWS / 64), 256, 0, stream>>>(
            obuf, wfcT_l, bfc_l, tmp, ROWS, DMODEL, DMODEL);
        ln_kernel<<<ROWS, 64, 0, stream>>>(tmp, x, xb, ln1_g + (size_t)l * DMODEL,
                                           ln1_b + (size_t)l * DMODEL);
        // h = relu(x @ W1 + b1)
        gemm_bf16_kernel<true, true, true><<<dim3(FFDIM / 128, ROWS / 128), 256, 0, stream>>>(
            xb, w1T_l, b1_l, hb, ROWS, FFDIM, DMODEL);
        // tmp = h @ W2 + b2
        gemm_bf16_m64_kernel<false, true, false><<<dim3(DMODEL / 128, ROWS / 64), 256, 0, stream>>>(
            hb, w2T_l, b2_l, tmp, ROWS, DMODEL, FFDIM);
        ln_kernel<<<ROWS, 64, 0, stream>>>(tmp, x, xb, ln2_g + (size_t)l * DMODEL,
                                           ln2_b + (size_t)l * DMODEL);
    }
}